// Round 4
// baseline (524.263 us; speedup 1.0000x reference)
//
#include <hip/hip_runtime.h>

// AlphaNet: B=65536, F=8, T=60 = 6 windows x 10.
// R4: transpose-first. kT: xb[B][480] -> xbT[480][B] (tiled, coalesced R+W).
// All later kernels read xbT columns: lane=sample -> 256B contiguous per instr.
//   kA: stats. Block=64 samples, 4 waves = roles (half h, phase p):
//       p=0 corr (28ch), p=1 per-feature (48ch). Per-window DPP flush of
//       sum/sumsq, end flush of max-triple stats -> LDS acc -> global atomics.
//   k2: fused BN-params + weight fold: w1s[608][30]=sc*w1^T, c0[30]=b1+sum(cst*w)
//       (max3(bn(h)) = sc*max3raw+sh valid since sc=g*rsqrt(var)>=0, g=1).
//   kB: recompute features, a[30] += v*w1s_row (wave-uniform s_load rows),
//       4-way LDS combine, relu-dot-w2, write out.
// ws floats: [0,304) stats | [304,336) c0 | [336,18576) w1s | [18688,..) xbT

#define NB 65536
#define EPS_F    1e-8f
#define BN_EPS_F 1e-5f

__device__ __forceinline__ float frcp(float x) {
  return __builtin_amdgcn_rcpf(x);
}

template<int Ctrl, int RowMask>
__device__ __forceinline__ float dpp_mov0(float v) {
  return __int_as_float(__builtin_amdgcn_update_dpp(
      0, __float_as_int(v), Ctrl, RowMask, 0xf, true));
}
// wave64 sum; result valid in lane 63. VALU-only (no LDS pipe).
__device__ __forceinline__ float wave_sum64(float v) {
  v += dpp_mov0<0x111, 0xf>(v);
  v += dpp_mov0<0x112, 0xf>(v);
  v += dpp_mov0<0x114, 0xf>(v);
  v += dpp_mov0<0x118, 0xf>(v);
  v += dpp_mov0<0x142, 0xa>(v);
  v += dpp_mov0<0x143, 0xc>(v);
  return v;
}

__host__ __device__ constexpr int UT(int i, int j) { return i*8 - i*(i-1)/2 + (j - i); }
__host__ __device__ constexpr int PIDX(int i, int j) { return i*7 - i*(i-1)/2 + (j - i - 1); }

// ---------------- kT: transpose xb[B][480] -> xbT[480][B] ----------------
__global__ void __launch_bounds__(256)
kT(const float* __restrict__ xb, float* __restrict__ xbT) {
  __shared__ float tile[64 * 61];
  const int by = blockIdx.x >> 3;   // sample tile (64)
  const int bx = blockIdx.x & 7;    // channel tile (60)
  const float* src = xb + (size_t)by * 64 * 480 + bx * 60;
  #pragma unroll
  for (int k = 0; k < 15; ++k) {
    int idx = k * 256 + threadIdx.x;      // 0..3839
    int i = idx / 60, j = idx - i * 60;   // i: sample 0..63, j: channel 0..59
    tile[i * 61 + j] = src[(size_t)i * 480 + j];
  }
  __syncthreads();
  float* dst = xbT + (size_t)(bx * 60) * NB + by * 64;
  #pragma unroll
  for (int k = 0; k < 15; ++k) {
    int idx = k * 256 + threadIdx.x;
    int jj = idx >> 6, ii = idx & 63;     // jj: channel, ii: sample
    dst[(size_t)jj * NB + ii] = tile[ii * 61 + jj];
  }
}

// ---------------- kA: batch statistics ----------------
// stats: [0,76) sum | [76,152) sumsq | [152,228) sum max3raw | [228,304) sumsq max3raw
__global__ void __launch_bounds__(256)
kA(const float* __restrict__ xbT, const float* __restrict__ cw,
   const float* __restrict__ cb, float* __restrict__ stats) {
  const int tid  = threadIdx.x;
  const int wave = tid >> 6, lane = tid & 63;
  const int role = __builtin_amdgcn_readfirstlane(wave);  // 0..3
  const int h    = role >> 1;      // half
  const int p    = role & 1;       // 0=corr, 1=per-feature
  const size_t s = (size_t)blockIdx.x * 64 + lane;
  const float* xh = xbT + (size_t)(h * 30) * NB + s;      // + (f*60 + tt)*NB
  const bool ll = (lane == 63);

  __shared__ float acc[304];
  for (int i = tid; i < 304; i += 256) acc[i] = 0.f;
  __syncthreads();

  if (p == 0) {
    // ---- corr channels 0..27 ----
    float mA[28];
    #pragma unroll
    for (int q = 0; q < 28; ++q) mA[q] = -3.0e38f;
    #pragma unroll
    for (int wl = 0; wl < 3; ++wl) {
      float sum[8], S[36];
      #pragma unroll
      for (int f = 0; f < 8; ++f) sum[f] = 0.f;
      #pragma unroll
      for (int k = 0; k < 36; ++k) S[k] = 0.f;
      #pragma unroll
      for (int t = 0; t < 10; ++t) {
        float x[8];
        #pragma unroll
        for (int f = 0; f < 8; ++f) x[f] = xh[(size_t)(f*60 + wl*10 + t) * NB];
        #pragma unroll
        for (int f = 0; f < 8; ++f) sum[f] += x[f];
        #pragma unroll
        for (int i = 0; i < 8; ++i)
          #pragma unroll
          for (int j = i; j < 8; ++j)
            S[UT(i,j)] = fmaf(x[i], x[j], S[UT(i,j)]);
      }
      float mu[8], sd[8];
      #pragma unroll
      for (int f = 0; f < 8; ++f) {
        mu[f] = sum[f] * 0.1f;
        sd[f] = sqrtf(fmaf(-mu[f], mu[f], S[UT(f,f)] * 0.1f) + EPS_F);
      }
      #pragma unroll
      for (int i = 0; i < 8; ++i)
        #pragma unroll
        for (int j = i + 1; j < 8; ++j) {
          float cov = fmaf(-mu[i], mu[j], S[UT(i,j)] * 0.1f);
          float v = cov * frcp(fmaf(sd[i], sd[j], EPS_F));
          int q = PIDX(i,j);
          float ts = wave_sum64(v);
          float tq = wave_sum64(v * v);
          if (ll) { atomicAdd(&acc[q], ts); atomicAdd(&acc[76+q], tq); }
          mA[q] = fmaxf(mA[q], v);
        }
    }
    #pragma unroll
    for (int q = 0; q < 28; ++q) {
      float tm = wave_sum64(mA[q]);
      float t2 = wave_sum64(mA[q] * mA[q]);
      if (ll) { atomicAdd(&acc[152+q], tm); atomicAdd(&acc[228+q], t2); }
    }
  } else {
    // ---- per-feature channels 28..75 (wl outer: cache order matches corr wave) ----
    float m48[48];
    #pragma unroll
    for (int k = 0; k < 48; ++k) m48[k] = -3.0e38f;
    #pragma unroll
    for (int wl = 0; wl < 3; ++wl) {
      #pragma unroll
      for (int f = 0; f < 8; ++f) {
        float x[10];
        #pragma unroll
        for (int t = 0; t < 10; ++t) x[t] = xh[(size_t)(f*60 + wl*10 + t) * NB];
        float sm = 0.f, sq = 0.f, wsm = 0.f;
        #pragma unroll
        for (int t = 0; t < 10; ++t) {
          sm += x[t];
          sq = fmaf(x[t], x[t], sq);
          wsm = fmaf(x[t], (float)(t+1) * (1.f/55.f), wsm);
        }
        float mu = sm * 0.1f;
        float sd = sqrtf(fmaf(-mu, mu, sq * 0.1f) + EPS_F);
        float vv[6];
        vv[0] = mu * frcp(sd + EPS_F);
        vv[1] = wsm;
        #pragma unroll
        for (int o = 0; o < 4; ++o) {
          float cv = cb[o];
          #pragma unroll
          for (int t = 0; t < 10; ++t) cv = fmaf(x[t], cw[o*10 + t], cv);
          vv[2+o] = cv;
        }
        #pragma unroll
        for (int k = 0; k < 6; ++k) {
          int ch = (k == 0) ? (28 + f) : (k == 1) ? (36 + f) : (44 + (k-2)*8 + f);
          float ts = wave_sum64(vv[k]);
          float tq = wave_sum64(vv[k] * vv[k]);
          if (ll) { atomicAdd(&acc[ch], ts); atomicAdd(&acc[76+ch], tq); }
          m48[f*6 + k] = fmaxf(m48[f*6 + k], vv[k]);
        }
      }
    }
    #pragma unroll
    for (int f = 0; f < 8; ++f)
      #pragma unroll
      for (int k = 0; k < 6; ++k) {
        int ch = (k == 0) ? (28 + f) : (k == 1) ? (36 + f) : (44 + (k-2)*8 + f);
        float tm = wave_sum64(m48[f*6 + k]);
        float t2 = wave_sum64(m48[f*6 + k] * m48[f*6 + k]);
        if (ll) { atomicAdd(&acc[152+ch], tm); atomicAdd(&acc[228+ch], t2); }
      }
  }

  __syncthreads();
  for (int i = tid; i < 304; i += 256) atomicAdd(&stats[i], acc[i]);
}

// ---------------- k2: fused BN params + weight fold ----------------
__global__ void k2(const float* __restrict__ stats,
    const float* __restrict__ bn1g, const float* __restrict__ bn1b,
    const float* __restrict__ bn4g, const float* __restrict__ bn4b,
    const float* __restrict__ bn6g, const float* __restrict__ bn6b,
    const float* __restrict__ bn9g, const float* __restrict__ bn9b,
    const float* __restrict__ bnmg, const float* __restrict__ bnmb,
    const float* __restrict__ w1, const float* __restrict__ b1,
    float* __restrict__ w1s, float* __restrict__ c0) {
  const int r = blockIdx.x;       // 0..607
  const int j = threadIdx.x;      // j<30 active
  const int c = (r < 456) ? (r / 6) : ((r - 456) >> 1);
  float g, b;
  if      (c < 28) { g = bn1g[c];    b = bn1b[c];    }
  else if (c < 36) { g = bn4g[c-28]; b = bn4b[c-28]; }
  else if (c < 44) { g = bn6g[c-36]; b = bn6b[c-36]; }
  else             { g = bn9g[c-44]; b = bn9b[c-44]; }
  const float in1 = 1.0f / (65536.0f * 6.0f);
  const float in2 = 1.0f / (65536.0f * 2.0f);
  float mean = stats[c] * in1;
  float var  = stats[76 + c] * in1 - mean * mean;
  float sc1  = g * rsqrtf(var + BN_EPS_F);
  float sh1  = b - mean * sc1;
  float sc, cst;
  if (r < 456) { sc = sc1; cst = sh1; }
  else {
    float mmr  = stats[152 + c] * in2;
    float vmr  = stats[228 + c] * in2 - mmr * mmr;
    float meanm = sc1 * mmr + sh1;
    float varm  = sc1 * sc1 * vmr;
    float scm = bnmg[c] * rsqrtf(varm + BN_EPS_F);
    float shm = bnmb[c] - meanm * scm;
    sc = sc1 * scm; cst = fmaf(scm, sh1, shm);
  }
  if (j < 30) {
    float w = w1[j * 608 + r];
    w1s[r * 30 + j] = sc * w;
    float ca = cst * w;
    if (r == 0) ca += b1[j];
    atomicAdd(&c0[j], ca);
  }
}

// ---------------- kB: features + MLP + output ----------------
__global__ void __launch_bounds__(256)
kB(const float* __restrict__ xbT, const float* __restrict__ cw,
   const float* __restrict__ cb, const float* __restrict__ w1s,
   const float* __restrict__ c0, const float* __restrict__ w2,
   const float* __restrict__ b2, float* __restrict__ out) {
  const int tid  = threadIdx.x;
  const int wave = tid >> 6, lane = tid & 63;
  const int role = __builtin_amdgcn_readfirstlane(wave);
  const int h    = role >> 1;
  const int p    = role & 1;
  const size_t s = (size_t)blockIdx.x * 64 + lane;
  const float* xh = xbT + (size_t)(h * 30) * NB + s;

  float a[30];
  #pragma unroll
  for (int j = 0; j < 30; ++j) a[j] = 0.f;

  if (p == 0) {
    float mA[28];
    #pragma unroll
    for (int q = 0; q < 28; ++q) mA[q] = -3.0e38f;
    #pragma unroll
    for (int wl = 0; wl < 3; ++wl) {
      float sum[8], S[36];
      #pragma unroll
      for (int f = 0; f < 8; ++f) sum[f] = 0.f;
      #pragma unroll
      for (int k = 0; k < 36; ++k) S[k] = 0.f;
      #pragma unroll
      for (int t = 0; t < 10; ++t) {
        float x[8];
        #pragma unroll
        for (int f = 0; f < 8; ++f) x[f] = xh[(size_t)(f*60 + wl*10 + t) * NB];
        #pragma unroll
        for (int f = 0; f < 8; ++f) sum[f] += x[f];
        #pragma unroll
        for (int i = 0; i < 8; ++i)
          #pragma unroll
          for (int j = i; j < 8; ++j)
            S[UT(i,j)] = fmaf(x[i], x[j], S[UT(i,j)]);
      }
      float mu[8], sd[8];
      #pragma unroll
      for (int f = 0; f < 8; ++f) {
        mu[f] = sum[f] * 0.1f;
        sd[f] = sqrtf(fmaf(-mu[f], mu[f], S[UT(f,f)] * 0.1f) + EPS_F);
      }
      #pragma unroll
      for (int i = 0; i < 8; ++i)
        #pragma unroll
        for (int j = i + 1; j < 8; ++j) {
          float cov = fmaf(-mu[i], mu[j], S[UT(i,j)] * 0.1f);
          float v = cov * frcp(fmaf(sd[i], sd[j], EPS_F));
          int q = PIDX(i,j);
          mA[q] = fmaxf(mA[q], v);
          const float* wr = w1s + (q*6 + h*3 + wl) * 30;   // uniform -> s_load
          #pragma unroll
          for (int j2 = 0; j2 < 30; ++j2) a[j2] = fmaf(v, wr[j2], a[j2]);
        }
    }
    #pragma unroll
    for (int q = 0; q < 28; ++q) {
      const float* wr = w1s + (456 + q*2 + h) * 30;
      #pragma unroll
      for (int j2 = 0; j2 < 30; ++j2) a[j2] = fmaf(mA[q], wr[j2], a[j2]);
    }
  } else {
    float m48[48];
    #pragma unroll
    for (int k = 0; k < 48; ++k) m48[k] = -3.0e38f;
    #pragma unroll
    for (int wl = 0; wl < 3; ++wl) {
      #pragma unroll
      for (int f = 0; f < 8; ++f) {
        float x[10];
        #pragma unroll
        for (int t = 0; t < 10; ++t) x[t] = xh[(size_t)(f*60 + wl*10 + t) * NB];
        float sm = 0.f, sq = 0.f, wsm = 0.f;
        #pragma unroll
        for (int t = 0; t < 10; ++t) {
          sm += x[t];
          sq = fmaf(x[t], x[t], sq);
          wsm = fmaf(x[t], (float)(t+1) * (1.f/55.f), wsm);
        }
        float mu = sm * 0.1f;
        float sd = sqrtf(fmaf(-mu, mu, sq * 0.1f) + EPS_F);
        float vv[6];
        vv[0] = mu * frcp(sd + EPS_F);
        vv[1] = wsm;
        #pragma unroll
        for (int o = 0; o < 4; ++o) {
          float cv = cb[o];
          #pragma unroll
          for (int t = 0; t < 10; ++t) cv = fmaf(x[t], cw[o*10 + t], cv);
          vv[2+o] = cv;
        }
        #pragma unroll
        for (int k = 0; k < 6; ++k) {
          int ch = (k == 0) ? (28 + f) : (k == 1) ? (36 + f) : (44 + (k-2)*8 + f);
          m48[f*6 + k] = fmaxf(m48[f*6 + k], vv[k]);
          const float* wr = w1s + (ch*6 + h*3 + wl) * 30;
          #pragma unroll
          for (int j2 = 0; j2 < 30; ++j2) a[j2] = fmaf(vv[k], wr[j2], a[j2]);
        }
      }
    }
    #pragma unroll
    for (int f = 0; f < 8; ++f)
      #pragma unroll
      for (int k = 0; k < 6; ++k) {
        int ch = (k == 0) ? (28 + f) : (k == 1) ? (36 + f) : (44 + (k-2)*8 + f);
        const float* wr = w1s + (456 + ch*2 + h) * 30;
        #pragma unroll
        for (int j2 = 0; j2 < 30; ++j2) a[j2] = fmaf(m48[f*6 + k], wr[j2], a[j2]);
      }
  }

  // ---- 4-way combine + layer 2 ----
  __shared__ float accW[4][64][31];
  #pragma unroll
  for (int j = 0; j < 30; ++j) accW[wave][lane][j] = a[j];
  __syncthreads();
  if (tid < 64) {
    float t = b2[0];
    #pragma unroll
    for (int j = 0; j < 30; ++j) {
      float hj = ((accW[0][tid][j] + accW[1][tid][j]) +
                  (accW[2][tid][j] + accW[3][tid][j])) + c0[j];
      t = fmaf(w2[j], fmaxf(hj, 0.f), t);
    }
    out[(size_t)blockIdx.x * 64 + tid] = t;
  }
}

// ================= launch =================

extern "C" void kernel_launch(void* const* d_in, const int* in_sizes, int n_in,
                              void* d_out, int out_size, void* d_ws, size_t ws_size,
                              hipStream_t stream) {
  (void)in_sizes; (void)n_in; (void)out_size; (void)ws_size;
  const float* xb   = (const float*)d_in[0];
  const float* cw   = (const float*)d_in[1];
  const float* cb   = (const float*)d_in[2];
  const float* bn1g = (const float*)d_in[3];
  const float* bn1b = (const float*)d_in[4];
  const float* bn4g = (const float*)d_in[5];
  const float* bn4b = (const float*)d_in[6];
  const float* bn6g = (const float*)d_in[7];
  const float* bn6b = (const float*)d_in[8];
  const float* bn9g = (const float*)d_in[9];
  const float* bn9b = (const float*)d_in[10];
  const float* bnmg = (const float*)d_in[11];
  const float* bnmb = (const float*)d_in[12];
  const float* w1   = (const float*)d_in[13];
  const float* b1   = (const float*)d_in[14];
  const float* w2   = (const float*)d_in[15];
  const float* b2   = (const float*)d_in[16];

  float* out   = (float*)d_out;
  float* ws    = (float*)d_ws;
  float* stats = ws;           // 304
  float* c0    = ws + 304;     // 32
  float* w1s   = ws + 336;     // 608*30 -> ends 18576
  float* xbT   = ws + 18688;   // 480*65536 (128B-aligned offset)

  hipMemsetAsync(ws, 0, 336 * sizeof(float), stream);
  kT<<<8192, 256, 0, stream>>>(xb, xbT);
  kA<<<1024, 256, 0, stream>>>(xbT, cw, cb, stats);
  k2<<<608, 32, 0, stream>>>(stats, bn1g, bn1b, bn4g, bn4b, bn6g, bn6b,
                             bn9g, bn9b, bnmg, bnmb, w1, b1, w1s, c0);
  kB<<<1024, 256, 0, stream>>>(xbT, cw, cb, w1s, c0, w2, b2, out);
}